// Round 4
// baseline (194.937 us; speedup 1.0000x reference)
//
#include <hip/hip_runtime.h>

// ---------------------------------------------------------------------------
// CirculantLinear, fused GEMM path, round 5: BARRIER-FREE wave-private GEMM.
//
// Karatsuba in frequency space: K1=(Xr+Xi)Er, K2=Xr(Ei-Er), K3=Xi(Ei+Er)
//   Or = K1-K3, Oi = K1+K2
// ONE flat K=5120 bf16 GEMM per output tile:
//   A  = Xp 4096 x 5120 = [Xs | Xr | Xi | X0 | X2]
//   B  = Bp 1024 x 5120 = [Er | Ei-Er | -(Ei+Er) | E0 | E2]   (row = y)
//
// Round-5 change: every prior round was limited by block-wide lockstep
// (barrier + shared staging couples all waves each K-step). Now each of the
// 4 waves is an INDEPENDENT 64x64x5120 mini-GEMM with PRIVATE LDS double
// buffers (4 waves x 2 bufs x (A 8KB + B 8KB) = 128 KB): stages its own
// tiles via global_load_lds, per-wave counted s_waitcnt vmcnt(16), NO
// s_barrier anywhere. M4N4 frags (ratio 2.0). 2 live acc groups + park of
// Or,Oi into the wave's own exclusive C region (read back in epilogue,
// wave-local ordering via vmcnt(0) only). ~2x L2 fetch duplication is
// absorbed by L2. Write-after-read on the private buffer is safe: stage is
// issued after the MFMA cluster that last read it (sched_barrier fences).
//
// ws: [0,40MiB) Xp bf16 4096x5120 ; [40,50MiB) Bp bf16 1024x5120
// ---------------------------------------------------------------------------

typedef __attribute__((ext_vector_type(8))) short bf16x8_t;
typedef __attribute__((ext_vector_type(4))) float f32x4_t;

#define NDIM 4096
#define TILE 128
#define BK 32

__device__ __forceinline__ unsigned short f2bf(float f) {
    unsigned int u = __builtin_bit_cast(unsigned int, f);
    u += 0x7fffu + ((u >> 16) & 1u);
    return (unsigned short)(u >> 16);
}

__device__ __forceinline__ void async_copy16(const void* g, void* l) {
    __builtin_amdgcn_global_load_lds(
        (const __attribute__((address_space(1))) void*)g,
        (__attribute__((address_space(3))) void*)l,
        16, 0, 0);
}

// ======================= PRIMARY (fused) path ==============================

// pre-pass: 4 mini-blocks per thread, 8-byte stores per panel.
__global__ __launch_bounds__(256) void pre_k(const float* __restrict__ x,
                                             const float* __restrict__ eig,
                                             unsigned short* __restrict__ xp,
                                             unsigned short* __restrict__ B) {
    const int t = threadIdx.x;
    if (blockIdx.x < 4096) {
        int gid = blockIdx.x * 256 + t;
        int b = gid >> 8, j0 = (gid & 255) << 2;
        const float4* src = (const float4*)x + ((size_t)b << 10) + j0;
        unsigned short S[4], R[4], Mi[4], Z[4], T[4];
#pragma unroll
        for (int q = 0; q < 4; ++q) {
            float4 v = src[q];
            float r = v.x - v.z, m = v.w - v.y;
            S[q]  = f2bf(r + m);                     // Xs = Xr+Xi
            R[q]  = f2bf(r);                         // Xr
            Mi[q] = f2bf(m);                         // Xi
            Z[q]  = f2bf(v.x + v.y + v.z + v.w);     // X0
            T[q]  = f2bf(v.x - v.y + v.z - v.w);     // X2
        }
        unsigned short* dst = xp + (size_t)b * 5120 + j0;
        *(ushort4*)(dst)        = *(const ushort4*)S;
        *(ushort4*)(dst + 1024) = *(const ushort4*)R;
        *(ushort4*)(dst + 2048) = *(const ushort4*)Mi;
        *(ushort4*)(dst + 3072) = *(const ushort4*)Z;
        *(ushort4*)(dst + 4096) = *(const ushort4*)T;
    } else {
        int gid = (blockIdx.x - 4096) * 256 + t;
        int y = gid >> 8, c0 = (gid & 255) << 2;
        const float4* src = (const float4*)eig + ((size_t)y << 10) + c0;
        unsigned short P0[4], P1[4], P2[4], P3[4], P4[4];
#pragma unroll
        for (int q = 0; q < 4; ++q) {
            float4 v = src[q];
            float r = v.x - v.z, m = v.w - v.y;      // Er, Ei
            P0[q] = f2bf(r);                         // Er
            P1[q] = f2bf(m - r);                     // Ei-Er
            P2[q] = f2bf(-(m + r));                  // -(Ei+Er)
            P3[q] = f2bf(v.x + v.y + v.z + v.w);     // E0
            P4[q] = f2bf(v.x - v.y + v.z - v.w);     // E2
        }
        unsigned short* dst = B + (size_t)y * 5120 + c0;
        *(ushort4*)(dst)        = *(const ushort4*)P0;
        *(ushort4*)(dst + 1024) = *(const ushort4*)P1;
        *(ushort4*)(dst + 2048) = *(const ushort4*)P2;
        *(ushort4*)(dst + 3072) = *(const ushort4*)P3;
        *(ushort4*)(dst + 4096) = *(const ushort4*)P4;
    }
}

// Fused GEMM + irfft epilogue. Grid: 256 blocks = 32 rowBlks x 8 colBlks.
// 4 independent waves, each a 64x64 tile with private LDS dbuf. NO barriers.
__global__ __launch_bounds__(256, 1) void gemm_f(
        const unsigned short* __restrict__ A,   // Xp 4096 x 5120
        const unsigned short* __restrict__ B,   // Bp 1024 x 5120
        float* __restrict__ C) {                // out 4096 x 4096
    // per wave: 2 bufs x (A 64x64 8KB | B 64x64 8KB) = 32 KB -> 128 KB total
    __shared__ char smem[4][32768];

    const int raw    = blockIdx.x;
    const int xcd    = raw & 7;
    const int idx    = raw >> 3;                 // [0,32)
    const int rowBlk = xcd * 4 + (idx >> 3);     // [0,32)
    const int colBlk = idx & 7;                  // [0,8)

    const int t    = threadIdx.x;
    const int lane = t & 63;
    const int w    = t >> 6;                     // [0,4)
    const int lr   = lane & 15;
    const int quad = lane >> 4;
    const int xr   = lr & 7;                     // read-side XOR swizzle key

    // wave-private tile origin
    const int wrow  = rowBlk * 128 + (w >> 1) * 64;   // A rows
    const int wcolY = colBlk * 128 + (w & 1) * 64;    // compressed y cols

    // staging lane geometry: instr j covers rows 8j..8j+7 of the 64-row tile;
    // lane l -> row 8j+(l>>3), LDS slot col16 = l&7. Global source col16 is
    // pre-swizzled: gcol16 = (l&7) ^ (row&7) = (l&7)^(l>>3)  (both-sides rule).
    const int sj = lane >> 3;                         // row within 8-row group
    const int sc = (lane & 7) ^ sj;                   // pre-swizzled col16
    const unsigned short* pa = A + (size_t)(wrow + sj) * 5120 + sc * 8;
    const unsigned short* pb = B + (size_t)(wcolY + sj) * 5120 + sc * 8;

    char* smw = &smem[w][0];
    char* dA  = smw + lane * 16;          // + j*1024, + buf*16384
    char* dB  = smw + 8192 + lane * 16;

    int koff = 0;   // next k (u16) to prefetch
    int cb   = 0;   // current buffer

    f32x4_t accA[4][4] = {};   // K1 -> Or ; then O0
    f32x4_t accB[4][4] = {};   // Oi ; then O2

#define STAGE_P(BUF)                                                     \
    {                                                                    \
        const unsigned short* pak = pa + koff;                           \
        const unsigned short* pbk = pb + koff;                           \
        char* da = dA + (BUF) * 16384;                                   \
        char* db = dB + (BUF) * 16384;                                   \
        _Pragma("unroll")                                                \
        for (int j = 0; j < 8; ++j) {                                    \
            async_copy16(pak + (size_t)j * 40960, da + j * 1024);        \
            async_copy16(pbk + (size_t)j * 40960, db + j * 1024);        \
        }                                                                \
        koff += 64;                                                      \
    }

#define COMPUTE_P(BUF, ACC)                                                   \
    {                                                                         \
        const char* ab = smw + (BUF) * 16384 + lr * 128;                      \
        const char* bb = smw + (BUF) * 16384 + 8192 + lr * 128;               \
        _Pragma("unroll")                                                     \
        for (int kk = 0; kk < 2; ++kk) {                                      \
            const int sw = ((((kk << 2) | quad)) ^ xr) << 4;                  \
            bf16x8_t af[4], bfv[4];                                           \
            _Pragma("unroll")                                                 \
            for (int i = 0; i < 4; ++i)                                       \
                af[i] = *(const bf16x8_t*)(ab + i * 2048 + sw);               \
            _Pragma("unroll")                                                 \
            for (int j = 0; j < 4; ++j)                                       \
                bfv[j] = *(const bf16x8_t*)(bb + j * 2048 + sw);              \
            __builtin_amdgcn_s_setprio(1);                                    \
            _Pragma("unroll")                                                 \
            for (int mt = 0; mt < 4; ++mt)                                    \
                _Pragma("unroll")                                             \
                for (int nt = 0; nt < 4; ++nt)                                \
                    ACC[mt][nt] = __builtin_amdgcn_mfma_f32_16x16x32_bf16(    \
                        af[mt], bfv[nt], ACC[mt][nt], 0, 0, 0);               \
            __builtin_amdgcn_s_setprio(0);                                    \
        }                                                                     \
    }

    // One self-paced step: wait own tile-t loads (tile t+1's 16 stay in
    // flight), compute, then stage tile t+2 into the buffer just consumed
    // (LDS write lands at VMEM-return, long after the earlier ds_reads
    // executed; sched_barrier keeps issue order). NO barrier anywhere.
#define STEP_P(ACC)                                            \
    {                                                          \
        asm volatile("s_waitcnt vmcnt(16)" ::: "memory");      \
        __builtin_amdgcn_sched_barrier(0);                     \
        COMPUTE_P(cb, ACC);                                    \
        __builtin_amdgcn_sched_barrier(0);                     \
        if (koff < 5120) STAGE_P(cb);                          \
        cb ^= 1;                                               \
    }

#define PHASE_P(ACC, NSTEP)                                    \
    _Pragma("unroll 1")                                        \
    for (int s2 = 0; s2 < (NSTEP); ++s2) STEP_P(ACC)

    // prologue: tiles 0,1 -> 32 wave-private loads in flight
    STAGE_P(0);
    STAGE_P(1);

    PHASE_P(accA, 16)               // k [   0,1024): K1 = Xs*Er
#pragma unroll
    for (int mt = 0; mt < 4; ++mt)
#pragma unroll
        for (int nt = 0; nt < 4; ++nt) accB[mt][nt] = accA[mt][nt];
    PHASE_P(accB, 16)               // k [1024,2048): += K2  -> Oi
    PHASE_P(accA, 16)               // k [2048,3072): += -K3 -> Or

    // ---- PARK Or (accA), Oi (accB) into the wave's own C region ----------
    // Wave region: rows [wrow,wrow+64) x final cols [wcolY*4, wcolY*4+256).
    // Park Or at region cols [0,64), Oi at [64,128). Wave-local only.
#pragma unroll
    for (int mt = 0; mt < 4; ++mt) {
#pragma unroll
        for (int r = 0; r < 4; ++r) {
            float* pr = C + (size_t)(wrow + mt * 16 + quad * 4 + r) * NDIM +
                        wcolY * 4;
#pragma unroll
            for (int nt = 0; nt < 4; ++nt) {
                pr[nt * 16 + lr]      = accA[mt][nt][r];   // Or
                pr[64 + nt * 16 + lr] = accB[mt][nt][r];   // Oi
            }
        }
    }
    // Drain everything once (park stores AND in-flight stage loads for the
    // next two tiles). Restores a clean vmcnt baseline for the counted waits.
    asm volatile("s_waitcnt vmcnt(0)" ::: "memory");
    {
        f32x4_t z = {0.f, 0.f, 0.f, 0.f};
#pragma unroll
        for (int mt = 0; mt < 4; ++mt)
#pragma unroll
            for (int nt = 0; nt < 4; ++nt) { accA[mt][nt] = z; accB[mt][nt] = z; }
    }

    PHASE_P(accA, 16)               // k [3072,4096): O0
    PHASE_P(accB, 15)               // k [4096,5088): O2 (first 15 steps)

    // tail step 79: only own tile-79 loads outstanding -> drain fully
    asm volatile("s_waitcnt vmcnt(0)" ::: "memory");
    __builtin_amdgcn_sched_barrier(0);
    COMPUTE_P(cb, accB);

#undef PHASE_P
#undef STEP_P
#undef COMPUTE_P
#undef STAGE_P

    // ---- read park back (wave-local; loads complete before any store) ----
    float por[4][4][4], poi[4][4][4];
#pragma unroll
    for (int mt = 0; mt < 4; ++mt) {
#pragma unroll
        for (int r = 0; r < 4; ++r) {
            const float* pr = C + (size_t)(wrow + mt * 16 + quad * 4 + r) * NDIM +
                              wcolY * 4;
#pragma unroll
            for (int nt = 0; nt < 4; ++nt) {
                por[mt][nt][r] = pr[nt * 16 + lr];
                poi[mt][nt][r] = pr[64 + nt * 16 + lr];
            }
        }
    }
    asm volatile("s_waitcnt vmcnt(0)" ::: "memory");

    // epilogue: irfft4 in registers, final-output float4 stores only.
#pragma unroll
    for (int mt = 0; mt < 4; ++mt) {
#pragma unroll
        for (int r = 0; r < 4; ++r) {
            float* dst = C + (size_t)(wrow + mt * 16 + quad * 4 + r) * NDIM;
#pragma unroll
            for (int nt = 0; nt < 4; ++nt) {
                int yc = wcolY + nt * 16 + lr;
                float O0 = accA[mt][nt][r], O2 = accB[mt][nt][r];
                float Or = por[mt][nt][r], Oi = poi[mt][nt][r];
                float4 o;
                o.x = 0.25f * (O0 + 2.0f * Or + O2);
                o.y = 0.25f * (O0 - 2.0f * Oi - O2);
                o.z = 0.25f * (O0 - 2.0f * Or + O2);
                o.w = 0.25f * (O0 + 2.0f * Oi - O2);
                *(float4*)(dst + 4 * yc) = o;
            }
        }
    }
}

// ======================= FALLBACK (round-2 path) ===========================

__global__ __launch_bounds__(256) void fwd_x_fb(const float* __restrict__ x,
                                                unsigned short* __restrict__ xp) {
    int gid = blockIdx.x * 256 + threadIdx.x;
    int b = gid >> 10, j = gid & 1023;
    float4 v = ((const float4*)x)[(size_t)b * 1024 + j];
    unsigned short* dst = xp + (size_t)b * NDIM + j;
    dst[0]    = f2bf(v.x + v.y + v.z + v.w);
    dst[1024] = f2bf(v.x - v.z);
    dst[2048] = f2bf(v.w - v.y);
    dst[3072] = f2bf(v.x - v.y + v.z - v.w);
}

__global__ __launch_bounds__(256) void build_b_fb(const float* __restrict__ eig,
                                                  unsigned short* __restrict__ B) {
    int gid = blockIdx.x * 256 + threadIdx.x;
    int y = gid >> 10, c = gid & 1023;
    float4 v = ((const float4*)eig)[(size_t)y * 1024 + c];
    float r = v.x - v.z, s = v.w - v.y;
    B[(size_t)y * 1024 + c] = f2bf(v.x + v.y + v.z + v.w);
    unsigned short* b1r = B + 1048576 + (size_t)y * 2048;
    b1r[c]        = f2bf(r);
    b1r[1024 + c] = f2bf(-s);
    unsigned short* b1i = B + 3145728 + (size_t)y * 2048;
    b1i[c]        = f2bf(s);
    b1i[1024 + c] = f2bf(r);
    B[5242880 + (size_t)y * 1024 + c] = f2bf(v.x - v.y + v.z - v.w);
}

__global__ __launch_bounds__(256, 2) void gemm_fb(
        const unsigned short* __restrict__ A,
        const unsigned short* __restrict__ B,
        float* __restrict__ C) {
    __shared__ unsigned short lA[TILE * BK];
    __shared__ unsigned short lB[TILE * BK];

    const int Ks[4]   = {1024, 2048, 2048, 1024};
    const int Aoff[4] = {0, 1024, 1024, 3072};
    const size_t Boff[4] = {0u, 1048576u, 3145728u, 5242880u};

    int lin = blockIdx.x;
    int seg, nseg, blkM;
    if (lin < 512) { seg = 1 + ((lin >> 3) & 1); nseg = lin & 7; blkM = lin >> 4; }
    else { int i = lin - 512; seg = ((i >> 3) & 1) * 3; nseg = i & 7; blkM = i >> 4; }

    const int K    = Ks[seg];
    const int aoff = Aoff[seg];
    const unsigned short* Bs = B + Boff[seg];

    const int t    = threadIdx.x;
    const int lane = t & 63;
    const int w    = t >> 6;
    const int wm   = (w >> 1) * 64;
    const int wn   = (w & 1) * 64;
    const int lr   = lane & 15;
    const int quad = lane >> 4;

    const int e0 = t * 8;
    const int r0 = e0 >> 5;
    const int c0 = e0 & 31;

    const unsigned short* pa0 = A + (size_t)(blkM * TILE + r0) * NDIM + aoff + c0;
    const unsigned short* pa1 = pa0 + (size_t)64 * NDIM;
    const unsigned short* pb0 = Bs + (size_t)(nseg * TILE + r0) * K + c0;
    const unsigned short* pb1 = pb0 + (size_t)64 * K;

    unsigned short* dA0 = &lA[e0];
    unsigned short* dA1 = &lA[2048 + e0];
    unsigned short* dB0 = &lB[e0];
    unsigned short* dB1 = &lB[2048 + e0];

    const unsigned short* la0 = &lA[(wm + lr) * BK + quad * 8];
    const unsigned short* lb0 = &lB[(wn + lr) * BK + quad * 8];

    f32x4_t acc[4][4] = {};

    for (int k0 = 0; k0 < K; k0 += BK) {
        async_copy16(pa0 + k0, dA0);
        async_copy16(pa1 + k0, dA1);
        async_copy16(pb0 + k0, dB0);
        async_copy16(pb1 + k0, dB1);
        asm volatile("s_waitcnt vmcnt(0)" ::: "memory");
        __syncthreads();

        bf16x8_t af[4], bfr[4];
#pragma unroll
        for (int i = 0; i < 4; ++i)
            af[i] = *(const bf16x8_t*)(la0 + i * 16 * BK);
#pragma unroll
        for (int i = 0; i < 4; ++i)
            bfr[i] = *(const bf16x8_t*)(lb0 + i * 16 * BK);

#pragma unroll
        for (int mt = 0; mt < 4; ++mt)
#pragma unroll
            for (int nt = 0; nt < 4; ++nt)
                acc[mt][nt] = __builtin_amdgcn_mfma_f32_16x16x32_bf16(
                    af[mt], bfr[nt], acc[mt][nt], 0, 0, 0);

        __syncthreads();
    }

    const int orow0 = blkM * TILE + wm + quad * 4;
    const int ocol0 = seg * 1024 + nseg * TILE + wn + lr;
#pragma unroll
    for (int mt = 0; mt < 4; ++mt) {
#pragma unroll
        for (int r = 0; r < 4; ++r) {
            float* dst = C + (size_t)(orow0 + mt * 16 + r) * NDIM + ocol0;
#pragma unroll
            for (int nt = 0; nt < 4; ++nt)
                dst[nt * 16] = acc[mt][nt][r];
        }
    }
}

__global__ __launch_bounds__(256) void post_fb(float* __restrict__ O) {
    float* row = O + (size_t)blockIdx.x * NDIM;
    const int t = threadIdx.x;
    float4 v0 = *(const float4*)(row + 4 * t);
    float4 vr = *(const float4*)(row + 1024 + 4 * t);
    float4 vi = *(const float4*)(row + 2048 + 4 * t);
    float4 v2 = *(const float4*)(row + 3072 + 4 * t);
    __syncthreads();
    const float* a0 = (const float*)&v0;
    const float* ar = (const float*)&vr;
    const float* ai = (const float*)&vi;
    const float* a2 = (const float*)&v2;
#pragma unroll
    for (int i = 0; i < 4; ++i) {
        float4 o;
        o.x = 0.25f * (a0[i] + 2.0f * ar[i] + a2[i]);
        o.y = 0.25f * (a0[i] - 2.0f * ai[i] - a2[i]);
        o.z = 0.25f * (a0[i] - 2.0f * ar[i] + a2[i]);
        o.w = 0.25f * (a0[i] + 2.0f * ai[i] - a2[i]);
        *(float4*)(row + 16 * t + 4 * i) = o;
    }
}

// ============================== launch =====================================

extern "C" void kernel_launch(void* const* d_in, const int* in_sizes, int n_in,
                              void* d_out, int out_size, void* d_ws, size_t ws_size,
                              hipStream_t stream) {
    const float* x   = (const float*)d_in[0];
    const float* eig = (const float*)d_in[1];
    float* out = (float*)d_out;

    const size_t NEED = (size_t)50 * 1024 * 1024;

    if (ws_size >= NEED) {
        unsigned short* Xp = (unsigned short*)d_ws;                      // 40 MiB
        unsigned short* Bp = (unsigned short*)((char*)d_ws + 41943040u); // 10 MiB

        pre_k<<<5120, 256, 0, stream>>>(x, eig, Xp, Bp);
        gemm_f<<<256, 256, 0, stream>>>(Xp, Bp, out);
    } else {
        unsigned short* Xp = (unsigned short*)d_ws;
        unsigned short* Bp = Xp + (size_t)NDIM * NDIM;

        fwd_x_fb<<<(NDIM * 1024) / 256, 256, 0, stream>>>(x, Xp);
        build_b_fb<<<(1024 * 1024) / 256, 256, 0, stream>>>(eig, Bp);
        gemm_fb<<<dim3(1024, 1), 256, 0, stream>>>(Xp, Bp, out);
        post_fb<<<NDIM, 256, 0, stream>>>(out);
    }
}

// Round 6
// 188.828 us; speedup vs baseline: 1.0324x; 1.0324x over previous
//
#include <hip/hip_runtime.h>

// ---------------------------------------------------------------------------
// CirculantLinear, fused GEMM path, round 7.
//
// Karatsuba in frequency space: K1=(Xr+Xi)Er, K2=Xr(Ei-Er), K3=Xi(Ei+Er)
//   Or = K1-K3, Oi = K1+K2
// ONE flat K=5120 bf16 GEMM per output tile:
//   A  = Xp 4096 x 5120 = [Xs | Xr | Xi | X0 | X2]
//   B  = Bp 1024 x 5120 = [Er | Ei-Er | -(Ei+Er) | E0 | E2]   (row = y)
// Accumulator target switches every 1024 k; irfft4 in the epilogue.
//
// Round-7 change: rounds 0-4 established a ~560-640 TF invariant across
// occupancy 4-20 waves/CU, four schedules, conflicts/no-conflicts -> the
// limiter is per-wave issue/latency in the ds_read->MFMA stream, and every
// round used 16x16x32 MFMA. This round: EXACT round-1 kernel (verified
// PASS, 70.4us) with ONLY the compute core swapped to mfma_f32_32x32x16
// (half the MFMA instructions, same LDS traffic, 2x matrix-pipe occupancy
// per read batch, 32x32 pipe ~20% faster per ubench). Staging, swizzle,
// phase loop, grid: byte-identical to round 1.
//
// ws: [0,40MiB) Xp bf16 4096x5120 ; [40,50MiB) Bp bf16 1024x5120
// ---------------------------------------------------------------------------

typedef __attribute__((ext_vector_type(8))) short bf16x8_t;
typedef __attribute__((ext_vector_type(4))) float f32x4_t;
typedef __attribute__((ext_vector_type(16))) float f32x16_t;

#define NDIM 4096
#define TILE 128
#define BK 32

__device__ __forceinline__ unsigned short f2bf(float f) {
    unsigned int u = __builtin_bit_cast(unsigned int, f);
    u += 0x7fffu + ((u >> 16) & 1u);
    return (unsigned short)(u >> 16);
}

__device__ __forceinline__ void async_copy16(const void* g, void* l) {
    __builtin_amdgcn_global_load_lds(
        (const __attribute__((address_space(1))) void*)g,
        (__attribute__((address_space(3))) void*)l,
        16, 0, 0);
}

// ======================= PRIMARY (fused) path ==============================

// pre-pass: 4 mini-blocks per thread, 8-byte stores per panel.
__global__ __launch_bounds__(256) void pre_k(const float* __restrict__ x,
                                             const float* __restrict__ eig,
                                             unsigned short* __restrict__ xp,
                                             unsigned short* __restrict__ B) {
    const int t = threadIdx.x;
    if (blockIdx.x < 4096) {
        int gid = blockIdx.x * 256 + t;
        int b = gid >> 8, j0 = (gid & 255) << 2;
        const float4* src = (const float4*)x + ((size_t)b << 10) + j0;
        unsigned short S[4], R[4], Mi[4], Z[4], T[4];
#pragma unroll
        for (int q = 0; q < 4; ++q) {
            float4 v = src[q];
            float r = v.x - v.z, m = v.w - v.y;
            S[q]  = f2bf(r + m);                     // Xs = Xr+Xi
            R[q]  = f2bf(r);                         // Xr
            Mi[q] = f2bf(m);                         // Xi
            Z[q]  = f2bf(v.x + v.y + v.z + v.w);     // X0
            T[q]  = f2bf(v.x - v.y + v.z - v.w);     // X2
        }
        unsigned short* dst = xp + (size_t)b * 5120 + j0;
        *(ushort4*)(dst)        = *(const ushort4*)S;
        *(ushort4*)(dst + 1024) = *(const ushort4*)R;
        *(ushort4*)(dst + 2048) = *(const ushort4*)Mi;
        *(ushort4*)(dst + 3072) = *(const ushort4*)Z;
        *(ushort4*)(dst + 4096) = *(const ushort4*)T;
    } else {
        int gid = (blockIdx.x - 4096) * 256 + t;
        int y = gid >> 8, c0 = (gid & 255) << 2;
        const float4* src = (const float4*)eig + ((size_t)y << 10) + c0;
        unsigned short P0[4], P1[4], P2[4], P3[4], P4[4];
#pragma unroll
        for (int q = 0; q < 4; ++q) {
            float4 v = src[q];
            float r = v.x - v.z, m = v.w - v.y;      // Er, Ei
            P0[q] = f2bf(r);                         // Er
            P1[q] = f2bf(m - r);                     // Ei-Er
            P2[q] = f2bf(-(m + r));                  // -(Ei+Er)
            P3[q] = f2bf(v.x + v.y + v.z + v.w);     // E0
            P4[q] = f2bf(v.x - v.y + v.z - v.w);     // E2
        }
        unsigned short* dst = B + (size_t)y * 5120 + c0;
        *(ushort4*)(dst)        = *(const ushort4*)P0;
        *(ushort4*)(dst + 1024) = *(const ushort4*)P1;
        *(ushort4*)(dst + 2048) = *(const ushort4*)P2;
        *(ushort4*)(dst + 3072) = *(const ushort4*)P3;
        *(ushort4*)(dst + 4096) = *(const ushort4*)P4;
    }
}

// Fused GEMM + irfft epilogue.
// Grid: 256 blocks = 32 rowBlks x 8 colBlks. 512 thr (8 waves, 2M x 4N),
// wave tile 64x32 as 2x1 fragments of 32x32, mfma_f32_32x32x16_bf16.
__global__ __launch_bounds__(512, 2) void gemm_f(
        const unsigned short* __restrict__ A,   // Xp 4096 x 5120
        const unsigned short* __restrict__ B,   // Bp 1024 x 5120
        float* __restrict__ C) {                // out 4096 x 4096
    // [buf][ A tile 128x64 u16 (16KB) | B tile 128x64 u16 (16KB) ]
    __shared__ unsigned short sm[2][16384];

    // XCD swizzle: xcd k gets rowBlks 4k..4k+3, all 8 colBlks (A-slab reuse)
    const int raw    = blockIdx.x;
    const int xcd    = raw & 7;
    const int idx    = raw >> 3;                 // [0,32)
    const int rowBlk = xcd * 4 + (idx >> 3);     // [0,32)
    const int colBlk = idx & 7;                  // [0,8)

    const int t    = threadIdx.x;
    const int lane = t & 63;
    const int w    = t >> 6;                     // [0,8)
    const int wm   = (w >> 2) * 64;              // 2 M-waves
    const int wn   = (w & 3) * 32;               // 4 N-waves
    const int c32  = lane & 31;                  // 32x32 row/col within frag
    const int hbit = lane >> 5;                  // k-half selector
    const int xr8  = lane & 7;                   // read-side XOR swizzle key

    // staging (VERBATIM round-1, verified): thread t loads 16B for LDS slot
    // (row=t>>3, col8=t&7); GLOBAL source is pre-swizzled
    // (col8g = col8 ^ (row&7)) so swizzled reads see logical data.
    const int srow = t >> 3;                                   // [0,64)
    const int scol = ((t & 7) ^ ((t >> 3) & 7)) << 3;          // u16 in BK=64
    const unsigned short* pa0 = A + (size_t)(rowBlk * 128 + srow) * 5120 + scol;
    const unsigned short* pa1 = pa0 + (size_t)64 * 5120;
    const unsigned short* pb0 = B + (size_t)(colBlk * 128 + srow) * 5120 + scol;
    const unsigned short* pb1 = pb0 + (size_t)64 * 5120;

    char* smb  = (char*)&sm[0][0];
    char* dstT = smb + (size_t)t * 16;

    int koff = 0;   // next k (u16) to prefetch
    int cur  = 0;

    f32x16_t aK1[2] = {};   // K1, becomes Or
    f32x16_t aOi[2];        // Oi = K1 + K2 (init by copy)
    f32x16_t aO0[2] = {};
    f32x16_t aO2[2] = {};

#define STAGE_F(BUF)                                           \
    {                                                          \
        char* d = dstT + (BUF) * 32768;                        \
        async_copy16(pa0 + koff, d);                           \
        async_copy16(pa1 + koff, d + 8192);                    \
        async_copy16(pb0 + koff, d + 16384);                   \
        async_copy16(pb1 + koff, d + 24576);                   \
        koff += 64;                                            \
    }

    // per K-step (BK=64): 4 k-windows of 16; per window: 2 A-frag reads
    // (rows wm+{0,32}+c32) + 1 B-frag read (rows wn+c32) + 2 MFMA 32x32x16.
    // chunk = (kw<<1)|hbit, swizzled by XOR lane&7 (= row&7 for all rows).
#define COMPUTE_F(BUF, ACC)                                                   \
    {                                                                         \
        const char* ab = smb + (BUF) * 32768 + (wm + c32) * 128;              \
        const char* bb = smb + (BUF) * 32768 + 16384 + (wn + c32) * 128;      \
        _Pragma("unroll")                                                     \
        for (int kw = 0; kw < 4; ++kw) {                                      \
            const int sw = ((((kw << 1) | hbit)) ^ xr8) << 4;                 \
            bf16x8_t a0 = *(const bf16x8_t*)(ab + sw);                        \
            bf16x8_t a1 = *(const bf16x8_t*)(ab + 4096 + sw);                 \
            bf16x8_t bv = *(const bf16x8_t*)(bb + sw);                        \
            ACC[0] = __builtin_amdgcn_mfma_f32_32x32x16_bf16(                 \
                a0, bv, ACC[0], 0, 0, 0);                                     \
            ACC[1] = __builtin_amdgcn_mfma_f32_32x32x16_bf16(                 \
                a1, bv, ACC[1], 0, 0, 0);                                     \
        }                                                                     \
    }

    // round-1 verified loop: STAGE(next) before compute(cur); one
    // vmcnt(0)+barrier per step.
#define PHASE_F(ACC, ISLAST)                                   \
    _Pragma("unroll 2")                                        \
    for (int s2 = 0; s2 < 16; ++s2) {                          \
        if (!(ISLAST) || s2 < 15) STAGE_F(cur ^ 1);            \
        COMPUTE_F(cur, ACC);                                   \
        asm volatile("s_waitcnt vmcnt(0)" ::: "memory");       \
        __syncthreads();                                       \
        cur ^= 1;                                              \
    }

    // prologue
    STAGE_F(0);
    asm volatile("s_waitcnt vmcnt(0)" ::: "memory");
    __syncthreads();

    PHASE_F(aK1, 0)                 // k [   0,1024): K1 = Xs*Er
#pragma unroll
    for (int m = 0; m < 2; ++m) aOi[m] = aK1[m];
    PHASE_F(aOi, 0)                 // k [1024,2048): += K2  -> Oi
    PHASE_F(aK1, 0)                 // k [2048,3072): += -K3 -> Or
    PHASE_F(aO0, 0)                 // k [3072,4096): O0
    PHASE_F(aO2, 1)                 // k [4096,5120): O2

#undef PHASE_F
#undef COMPUTE_F
#undef STAGE_F

    // epilogue: irfft4 in registers, final-output float4 stores only.
    // 32x32 C/D map (m74/m101): col = lane&31, row = (reg&3)+8*(reg>>2)+4*hbit
    const int yc = colBlk * 128 + wn + c32;          // compressed col
#pragma unroll
    for (int m = 0; m < 2; ++m) {
#pragma unroll
        for (int reg = 0; reg < 16; ++reg) {
            int row = rowBlk * 128 + wm + m * 32 +
                      (reg & 3) + 8 * (reg >> 2) + 4 * hbit;
            float O0 = aO0[m][reg], Or = aK1[m][reg];
            float Oi = aOi[m][reg], O2 = aO2[m][reg];
            float4 o;
            o.x = 0.25f * (O0 + 2.0f * Or + O2);
            o.y = 0.25f * (O0 - 2.0f * Oi - O2);
            o.z = 0.25f * (O0 - 2.0f * Or + O2);
            o.w = 0.25f * (O0 + 2.0f * Oi - O2);
            *(float4*)(C + (size_t)row * NDIM + 4 * yc) = o;
        }
    }
}

// ======================= FALLBACK (round-2 path) ===========================

__global__ __launch_bounds__(256) void fwd_x_fb(const float* __restrict__ x,
                                                unsigned short* __restrict__ xp) {
    int gid = blockIdx.x * 256 + threadIdx.x;
    int b = gid >> 10, j = gid & 1023;
    float4 v = ((const float4*)x)[(size_t)b * 1024 + j];
    unsigned short* dst = xp + (size_t)b * NDIM + j;
    dst[0]    = f2bf(v.x + v.y + v.z + v.w);
    dst[1024] = f2bf(v.x - v.z);
    dst[2048] = f2bf(v.w - v.y);
    dst[3072] = f2bf(v.x - v.y + v.z - v.w);
}

__global__ __launch_bounds__(256) void build_b_fb(const float* __restrict__ eig,
                                                  unsigned short* __restrict__ B) {
    int gid = blockIdx.x * 256 + threadIdx.x;
    int y = gid >> 10, c = gid & 1023;
    float4 v = ((const float4*)eig)[(size_t)y * 1024 + c];
    float r = v.x - v.z, s = v.w - v.y;
    B[(size_t)y * 1024 + c] = f2bf(v.x + v.y + v.z + v.w);
    unsigned short* b1r = B + 1048576 + (size_t)y * 2048;
    b1r[c]        = f2bf(r);
    b1r[1024 + c] = f2bf(-s);
    unsigned short* b1i = B + 3145728 + (size_t)y * 2048;
    b1i[c]        = f2bf(s);
    b1i[1024 + c] = f2bf(r);
    B[5242880 + (size_t)y * 1024 + c] = f2bf(v.x - v.y + v.z - v.w);
}

__global__ __launch_bounds__(256, 2) void gemm_fb(
        const unsigned short* __restrict__ A,
        const unsigned short* __restrict__ B,
        float* __restrict__ C) {
    __shared__ unsigned short lA[TILE * BK];
    __shared__ unsigned short lB[TILE * BK];

    const int Ks[4]   = {1024, 2048, 2048, 1024};
    const int Aoff[4] = {0, 1024, 1024, 3072};
    const size_t Boff[4] = {0u, 1048576u, 3145728u, 5242880u};

    int lin = blockIdx.x;
    int seg, nseg, blkM;
    if (lin < 512) { seg = 1 + ((lin >> 3) & 1); nseg = lin & 7; blkM = lin >> 4; }
    else { int i = lin - 512; seg = ((i >> 3) & 1) * 3; nseg = i & 7; blkM = i >> 4; }

    const int K    = Ks[seg];
    const int aoff = Aoff[seg];
    const unsigned short* Bs = B + Boff[seg];

    const int t    = threadIdx.x;
    const int lane = t & 63;
    const int w    = t >> 6;
    const int wm   = (w >> 1) * 64;
    const int wn   = (w & 1) * 64;
    const int lr   = lane & 15;
    const int quad = lane >> 4;

    const int e0 = t * 8;
    const int r0 = e0 >> 5;
    const int c0 = e0 & 31;

    const unsigned short* pa0 = A + (size_t)(blkM * TILE + r0) * NDIM + aoff + c0;
    const unsigned short* pa1 = pa0 + (size_t)64 * NDIM;
    const unsigned short* pb0 = Bs + (size_t)(nseg * TILE + r0) * K + c0;
    const unsigned short* pb1 = pb0 + (size_t)64 * K;

    unsigned short* dA0 = &lA[e0];
    unsigned short* dA1 = &lA[2048 + e0];
    unsigned short* dB0 = &lB[e0];
    unsigned short* dB1 = &lB[2048 + e0];

    const unsigned short* la0 = &lA[(wm + lr) * BK + quad * 8];
    const unsigned short* lb0 = &lB[(wn + lr) * BK + quad * 8];

    f32x4_t acc[4][4] = {};

    for (int k0 = 0; k0 < K; k0 += BK) {
        async_copy16(pa0 + k0, dA0);
        async_copy16(pa1 + k0, dA1);
        async_copy16(pb0 + k0, dB0);
        async_copy16(pb1 + k0, dB1);
        asm volatile("s_waitcnt vmcnt(0)" ::: "memory");
        __syncthreads();

        bf16x8_t af[4], bfr[4];
#pragma unroll
        for (int i = 0; i < 4; ++i)
            af[i] = *(const bf16x8_t*)(la0 + i * 16 * BK);
#pragma unroll
        for (int i = 0; i < 4; ++i)
            bfr[i] = *(const bf16x8_t*)(lb0 + i * 16 * BK);

#pragma unroll
        for (int mt = 0; mt < 4; ++mt)
#pragma unroll
            for (int nt = 0; nt < 4; ++nt)
                acc[mt][nt] = __builtin_amdgcn_mfma_f32_16x16x32_bf16(
                    af[mt], bfr[nt], acc[mt][nt], 0, 0, 0);

        __syncthreads();
    }

    const int orow0 = blkM * TILE + wm + quad * 4;
    const int ocol0 = seg * 1024 + nseg * TILE + wn + lr;
#pragma unroll
    for (int mt = 0; mt < 4; ++mt) {
#pragma unroll
        for (int r = 0; r < 4; ++r) {
            float* dst = C + (size_t)(orow0 + mt * 16 + r) * NDIM + ocol0;
#pragma unroll
            for (int nt = 0; nt < 4; ++nt)
                dst[nt * 16] = acc[mt][nt][r];
        }
    }
}

__global__ __launch_bounds__(256) void post_fb(float* __restrict__ O) {
    float* row = O + (size_t)blockIdx.x * NDIM;
    const int t = threadIdx.x;
    float4 v0 = *(const float4*)(row + 4 * t);
    float4 vr = *(const float4*)(row + 1024 + 4 * t);
    float4 vi = *(const float4*)(row + 2048 + 4 * t);
    float4 v2 = *(const float4*)(row + 3072 + 4 * t);
    __syncthreads();
    const float* a0 = (const float*)&v0;
    const float* ar = (const float*)&vr;
    const float* ai = (const float*)&vi;
    const float* a2 = (const float*)&v2;
#pragma unroll
    for (int i = 0; i < 4; ++i) {
        float4 o;
        o.x = 0.25f * (a0[i] + 2.0f * ar[i] + a2[i]);
        o.y = 0.25f * (a0[i] - 2.0f * ai[i] - a2[i]);
        o.z = 0.25f * (a0[i] - 2.0f * ar[i] + a2[i]);
        o.w = 0.25f * (a0[i] + 2.0f * ai[i] - a2[i]);
        *(float4*)(row + 16 * t + 4 * i) = o;
    }
}

// ============================== launch =====================================

extern "C" void kernel_launch(void* const* d_in, const int* in_sizes, int n_in,
                              void* d_out, int out_size, void* d_ws, size_t ws_size,
                              hipStream_t stream) {
    const float* x   = (const float*)d_in[0];
    const float* eig = (const float*)d_in[1];
    float* out = (float*)d_out;

    const size_t NEED = (size_t)50 * 1024 * 1024;

    if (ws_size >= NEED) {
        unsigned short* Xp = (unsigned short*)d_ws;                      // 40 MiB
        unsigned short* Bp = (unsigned short*)((char*)d_ws + 41943040u); // 10 MiB

        pre_k<<<5120, 256, 0, stream>>>(x, eig, Xp, Bp);
        gemm_f<<<256, 512, 0, stream>>>(Xp, Bp, out);
    } else {
        unsigned short* Xp = (unsigned short*)d_ws;
        unsigned short* Bp = Xp + (size_t)NDIM * NDIM;

        fwd_x_fb<<<(NDIM * 1024) / 256, 256, 0, stream>>>(x, Xp);
        build_b_fb<<<(1024 * 1024) / 256, 256, 0, stream>>>(eig, Bp);
        gemm_fb<<<dim3(1024, 1), 256, 0, stream>>>(Xp, Bp, out);
        post_fb<<<NDIM, 256, 0, stream>>>(out);
    }
}